// Round 11
// baseline (316.902 us; speedup 1.0000x reference)
//
#include <hip/hip_runtime.h>
#include <stdint.h>

// Problem constants (reference: B=2, S=2048, D=1024, H=16, DK=64)
#define B_  2
#define S_  2048
#define D_  1024
#define H_  16
#define DK_ 64
#define PERHEAD (S_ * DK_)  // 131072 elems per (b,h)

// exp(x*0.125) = exp2(x * 0.125*log2(e))
#define EXP2SCALE 0.18033688011112042f

typedef __attribute__((ext_vector_type(8))) short short8;   // 8 bf16 = 4 VGPRs (MFMA A/B frag)
typedef __attribute__((ext_vector_type(4))) float floatx4;  // MFMA C/D frag

#define MFMA16(a, b, c) __builtin_amdgcn_mfma_f32_16x16x32_bf16((a), (b), (c), 0, 0, 0)

// async global->LDS, 16B per lane. Global src is PER-LANE; LDS dst is wave-uniform
// base + lane*16 (m104).
__device__ __forceinline__ void gload_lds16(const void* g, void* lds) {
  __builtin_amdgcn_global_load_lds(
      (__attribute__((address_space(1))) void*)(void*)g,
      (__attribute__((address_space(3))) void*)lds, 16, 0, 0);
}

__device__ __forceinline__ unsigned short f2bf(float f) {
  union { float f; unsigned int u; } v;
  v.f = f;
  unsigned int r = v.u + 0x7fffu + ((v.u >> 16) & 1u);
  return (unsigned short)(r >> 16);
}

// pack two positive f32 into two bf16 (round-half-up: +0x8000 then take hi16 via v_perm)
__device__ __forceinline__ unsigned int pack_bf16_rhu(float e0, float e1) {
  unsigned int u0 = __float_as_uint(e0) + 0x8000u;
  unsigned int u1 = __float_as_uint(e1) + 0x8000u;
  return __builtin_amdgcn_perm(u1, u0, 0x07060302);  // {u1.hi16, u0.hi16}
}

// ---------------- single batched cast fp32 -> bf16 (7 tensors, one launch) ----------
// z 0..2: token inputs (n4 = NT/4 quads); z 3..6: weights (n4w = NW/4 quads).
__global__ void cast_all(const float* __restrict__ a0, const float* __restrict__ a1,
                         const float* __restrict__ a2, const float* __restrict__ a3,
                         const float* __restrict__ a4, const float* __restrict__ a5,
                         const float* __restrict__ a6,
                         unsigned short* __restrict__ o0, unsigned short* __restrict__ o1,
                         unsigned short* __restrict__ o2, unsigned short* __restrict__ o3,
                         unsigned short* __restrict__ o4, unsigned short* __restrict__ o5,
                         unsigned short* __restrict__ o6,
                         int n4tok, int n4w) {
  const int z = blockIdx.z;
  const float* in = (z == 0) ? a0 : (z == 1) ? a1 : (z == 2) ? a2 : (z == 3) ? a3
                    : (z == 4) ? a4 : (z == 5) ? a5 : a6;
  unsigned short* out = (z == 0) ? o0 : (z == 1) ? o1 : (z == 2) ? o2 : (z == 3) ? o3
                        : (z == 4) ? o4 : (z == 5) ? o5 : o6;
  const int n4 = (z < 3) ? n4tok : n4w;
  int i = blockIdx.x * 256 + threadIdx.x;
  if (i < n4) {
    float4 f = ((const float4*)in)[i];
    uint2 p;
    p.x = (unsigned int)f2bf(f.x) | ((unsigned int)f2bf(f.y) << 16);
    p.y = (unsigned int)f2bf(f.z) | ((unsigned int)f2bf(f.w) << 16);
    ((uint2*)out)[i] = p;
  }
}

// Fragment-ordered layouts (16x16x32 MFMA operand fragments; one frag = 16 rows x
// 32 k x bf16 = 512 elems = 64 lane-ordered 16B chunks; chunk L = row(L&15),
// k = (L>>4)*8..+7). Reader: ds/global _b128 at base + lane*16 -> conflict-free.
//
// Qf/Kf per (b,h): frag(sblk = s>>4, ks = dk>>5):  idx = sblk*2 + ks
// Vf    per (b,h): frag(kblk = key>>5, db = dk>>4): idx = kblk*4 + db  (rows = dk)

// ---------------- shared GEMM core: 128x128 tile, BK=32, 4 waves each 64x64 ----------
__device__ __forceinline__ void gemm_core(const unsigned short* __restrict__ A,
                                          const unsigned short* __restrict__ Bw,
                                          unsigned short* lA, unsigned short* lB,
                                          int m0, int n0, int tid, int lane, int wave,
                                          floatx4 acc[4][4]) {
  const int wm = (wave >> 1) * 64;
  const int wn = (wave & 1) * 64;
  for (int k0 = 0; k0 < D_; k0 += 32) {
#pragma unroll
    for (int l = 0; l < 2; ++l) {
      int c = l * 256 + tid;
      int row = c >> 2, cb = (c & 3) * 16;
      const char* ga = (const char*)A + ((size_t)(m0 + row) * D_ + k0) * 2 + cb;
      gload_lds16(ga, (char*)lA + (size_t)(l * 256 + wave * 64) * 16);
      const char* gb = (const char*)Bw + ((size_t)(n0 + row) * D_ + k0) * 2 + cb;
      gload_lds16(gb, (char*)lB + (size_t)(l * 256 + wave * 64) * 16);
    }
    __syncthreads();
    short8 af[4], bf_[4];
#pragma unroll
    for (int mt = 0; mt < 4; ++mt)
      af[mt] = *(const short8*)&lA[(wm + mt * 16 + (lane & 15)) * 32 + (lane >> 4) * 8];
#pragma unroll
    for (int nt = 0; nt < 4; ++nt)
      bf_[nt] = *(const short8*)&lB[(wn + nt * 16 + (lane & 15)) * 32 + (lane >> 4) * 8];
#pragma unroll
    for (int mt = 0; mt < 4; ++mt)
#pragma unroll
      for (int nt = 0; nt < 4; ++nt)
        acc[mt][nt] = MFMA16(af[mt], bf_[nt], acc[mt][nt]);
    __syncthreads();
  }
}

// ---------------- fused QKV projection: z selects (A, W, Out, epilogue) ----------------
// XCD swizzle (r8): XCD owns m-tiles [xcd*4, xcd*4+4) for all n, z slowest ->
// hot set ~3 MB (A panel 1 MB + B 2 MB), L2-resident. 768 = 8 xcd x 8 n x 4 m x 3 z.
// (256,3) since r9: grid = exactly 3 blocks/CU.
__launch_bounds__(256, 3)
__global__ void gemm_qkv(const unsigned short* __restrict__ qi, const unsigned short* __restrict__ ki,
                         const unsigned short* __restrict__ vi,
                         const unsigned short* __restrict__ Wq, const unsigned short* __restrict__ Wk,
                         const unsigned short* __restrict__ Wv,
                         unsigned short* __restrict__ Qf, unsigned short* __restrict__ Kf,
                         unsigned short* __restrict__ Vf) {
  __shared__ unsigned short lA[128 * 32];
  __shared__ unsigned short lB[128 * 32];
  const int f = blockIdx.x + 8 * blockIdx.y + 256 * blockIdx.z;
  const int xcd = f & 7, j = f >> 3;              // j in [0,96)
  const int n0 = (j & 7) * 128;                   // n-tile
  const int m0 = (xcd * 4 + ((j >> 3) & 3)) * 128;  // m-tile: XCD-chunked
  const int z  = j >> 5;                          // 0..2, slowest
  const unsigned short* A  = (z == 0) ? qi : (z == 1) ? ki : vi;
  const unsigned short* Bw = (z == 0) ? Wq : (z == 1) ? Wk : Wv;
  unsigned short* O        = (z == 0) ? Qf : (z == 1) ? Kf : Vf;
  const int tid = threadIdx.x, lane = tid & 63, wave = tid >> 6;
  const int wm = (wave >> 1) * 64, wn = (wave & 1) * 64;

  floatx4 acc[4][4] = {};
  gemm_core(A, Bw, lA, lB, m0, n0, tid, lane, wave, acc);

  if (z < 2) {  // Qf/Kf fragment layout
#pragma unroll
    for (int mt = 0; mt < 4; ++mt)
#pragma unroll
      for (int nt = 0; nt < 4; ++nt)
#pragma unroll
        for (int r = 0; r < 4; ++r) {
          int row = m0 + wm + mt * 16 + (lane >> 4) * 4 + r;  // token
          int col = n0 + wn + nt * 16 + (lane & 15);          // e
          int b = row >> 11, s = row & (S_ - 1);
          int h = col >> 6,  dk = col & 63;
          size_t base = (size_t)(b * H_ + h) * PERHEAD;
          int frag = (s >> 4) * 2 + (dk >> 5);
          int lp = (s & 15) | (((dk >> 3) & 3) << 4);
          O[base + (size_t)frag * 512 + lp * 8 + (dk & 7)] = f2bf(acc[mt][nt][r]);
        }
  } else {  // Vf fragment layout (rows = dk, k = key)
#pragma unroll
    for (int mt = 0; mt < 4; ++mt)
#pragma unroll
      for (int nt = 0; nt < 4; ++nt) {
        int row0 = m0 + wm + mt * 16 + (lane >> 4) * 4;  // 4 consecutive keys
        int col  = n0 + wn + nt * 16 + (lane & 15);
        int b = row0 >> 11, key0 = row0 & (S_ - 1);
        int h = col >> 6,   dk = col & 63;
        size_t base = (size_t)(b * H_ + h) * PERHEAD;
        int frag = (key0 >> 5) * 4 + (dk >> 4);
        int lp = (dk & 15) | (((key0 >> 3) & 3) << 4);
        unsigned long long pk =
            (unsigned long long)f2bf(acc[mt][nt][0]) |
            ((unsigned long long)f2bf(acc[mt][nt][1]) << 16) |
            ((unsigned long long)f2bf(acc[mt][nt][2]) << 32) |
            ((unsigned long long)f2bf(acc[mt][nt][3]) << 48);
        *(unsigned long long*)&O[base + (size_t)frag * 512 + lp * 8 + (key0 & 7)] = pk;
      }
  }
}

// ---------------- output projection: fp32 row-major ----------------
// r9: 64x128 tile, 512 blocks = 2/CU; XCD owns m-tiles [xcd*8, xcd*8+8).
__launch_bounds__(256, 2)
__global__ void gemm_out(const unsigned short* __restrict__ A, const unsigned short* __restrict__ Bw,
                         float* __restrict__ O) {
  __shared__ unsigned short lA[64 * 32];
  __shared__ unsigned short lB[128 * 32];
  const int f = blockIdx.x + 8 * blockIdx.y;      // grid (8, 64) = 512 blocks
  const int xcd = f & 7, j = f >> 3;              // j in [0,64)
  const int n0 = (j & 7) * 128;
  const int m0 = (xcd * 8 + (j >> 3)) * 64;       // m-tile (64 rows): XCD-chunked
  const int tid = threadIdx.x, lane = tid & 63, wave = tid >> 6;
  const int wm = (wave >> 1) * 32, wn = (wave & 1) * 64;
  floatx4 acc[2][4] = {};
  for (int k0 = 0; k0 < D_; k0 += 32) {
    {  // A: 64x32 tile = 256 x 16B chunks, one per thread
      int c = tid;
      int row = c >> 2, cb = (c & 3) * 16;
      const char* ga = (const char*)A + ((size_t)(m0 + row) * D_ + k0) * 2 + cb;
      gload_lds16(ga, (char*)lA + (size_t)(wave * 64) * 16);
    }
#pragma unroll
    for (int l = 0; l < 2; ++l) {  // B: 128x32 tile = 512 chunks, two per thread
      int c = l * 256 + tid;
      int row = c >> 2, cb = (c & 3) * 16;
      const char* gb = (const char*)Bw + ((size_t)(n0 + row) * D_ + k0) * 2 + cb;
      gload_lds16(gb, (char*)lB + (size_t)(l * 256 + wave * 64) * 16);
    }
    __syncthreads();
    short8 af[2], bf_[4];
#pragma unroll
    for (int mt = 0; mt < 2; ++mt)
      af[mt] = *(const short8*)&lA[(wm + mt * 16 + (lane & 15)) * 32 + (lane >> 4) * 8];
#pragma unroll
    for (int nt = 0; nt < 4; ++nt)
      bf_[nt] = *(const short8*)&lB[(wn + nt * 16 + (lane & 15)) * 32 + (lane >> 4) * 8];
#pragma unroll
    for (int mt = 0; mt < 2; ++mt)
#pragma unroll
      for (int nt = 0; nt < 4; ++nt)
        acc[mt][nt] = MFMA16(af[mt], bf_[nt], acc[mt][nt]);
    __syncthreads();
  }
#pragma unroll
  for (int mt = 0; mt < 2; ++mt)
#pragma unroll
    for (int nt = 0; nt < 4; ++nt)
#pragma unroll
      for (int r = 0; r < 4; ++r) {
        int row = m0 + wm + mt * 16 + (lane >> 4) * 4 + r;
        int col = n0 + wn + nt * 16 + (lane & 15);
        O[(size_t)row * D_ + col] = acc[mt][nt][r];
      }
}

// ---------------- Pass 1: Zl[b,q,k] = fp16( log2( sum_h exp2(s*C) ) ) ----------------
// r8: k-tile 64, 1024 blocks = 4 blocks/CU, (256,4). Kept (part of 301.0 best).
__launch_bounds__(256, 4)
__global__ void compute_z(const unsigned short* __restrict__ Qf,
                          const unsigned short* __restrict__ Kf,
                          unsigned short* __restrict__ Zl) {
  const int tid = threadIdx.x, lane = tid & 63, wave = tid >> 6;
  const int k0 = blockIdx.x * 64, q0 = blockIdx.y * 128, b = blockIdx.z;

  floatx4 zacc[2][4] = {};
  const short8* qbase = (const short8*)Qf + (size_t)b * H_ * (PERHEAD / 8)
                        + ((q0 >> 4) + wave * 2) * 128 + lane;
  const short8* kbase = (const short8*)Kf + (size_t)b * H_ * (PERHEAD / 8)
                        + (k0 >> 4) * 128 + lane;

#pragma unroll 1
  for (int h = 0; h < H_; ++h) {
    short8 qf0 = qbase[0], qf1 = qbase[64];    // sq=0, ks=0/1
    short8 qf2 = qbase[128], qf3 = qbase[192]; // sq=1, ks=0/1
    short8 kst[4][2];
#pragma unroll
    for (int kb = 0; kb < 4; ++kb) {
      kst[kb][0] = kbase[kb * 128];
      kst[kb][1] = kbase[kb * 128 + 64];
    }
#pragma unroll
    for (int kb = 0; kb < 4; ++kb) {
      floatx4 s0 = {}, s1 = {};
      s0 = MFMA16(qf0, kst[kb][0], s0);
      s0 = MFMA16(qf1, kst[kb][1], s0);
      s1 = MFMA16(qf2, kst[kb][0], s1);
      s1 = MFMA16(qf3, kst[kb][1], s1);
#pragma unroll
      for (int r = 0; r < 4; ++r) {
        zacc[0][kb][r] += exp2f(s0[r] * EXP2SCALE);
        zacc[1][kb][r] += exp2f(s1[r] * EXP2SCALE);
      }
    }
    qbase += PERHEAD / 8;
    kbase += PERHEAD / 8;
  }

#pragma unroll
  for (int sq = 0; sq < 2; ++sq)
#pragma unroll
    for (int kb = 0; kb < 4; ++kb)
#pragma unroll
      for (int r = 0; r < 4; ++r) {
        int q = q0 + wave * 32 + sq * 16 + (lane >> 4) * 4 + r;
        int k = k0 + kb * 16 + (lane & 15);
        union { _Float16 h; unsigned short u; } cv;
        cv.h = (_Float16)log2f(zacc[sq][kb][r]);
        Zl[((size_t)b * S_ + q) * S_ + k] = cv.u;
      }
}

// ---------------- Pass 2: x^T = exp2(s*C - Lz) @ V ----------------
// Round-11: K/V prefetch moved from VGPRs to ASYNC global_load_lds staging.
// Diagnosis: r0-r10 all moved K/V via register prefetch; compiler collapsed the
// rotation every time (VGPR_Count 40-64 << live state) and sank loads to use ->
// L2 latency exposed on the serial chain. global_load_lds holds the prefetch in
// the HW DMA queue instead (compiler can't collapse it); each wave stages the
// exact 4 fragments (K0,K1,V0,V1) it consumes into a wave-private LDS region
// (linear lane*16 layout, gload_lds-compatible AND conflict-free ds_read_b128),
// so NO extra barrier: staging for t+1 issues at iter start, and the existing
// P-barrier's mandatory vmcnt(0) drain covers completion with ~1 full iteration
// of slack (m97 GEMM mechanism). Zl/P/epilogue byte-identical to r0.
// LDS 16->48 KB: still 3 blocks/CU. Head partition preserved (f mod 8 = h mod 8).
__launch_bounds__(256, 3)
__global__ void attn_pv(const unsigned short* __restrict__ Qf,
                        const unsigned short* __restrict__ Kf,
                        const unsigned short* __restrict__ Vf,
                        const unsigned short* __restrict__ Zl,
                        unsigned short* __restrict__ X) {
  __shared__ unsigned short lP[2 * 4096];        // 16 KB: 2 bufs x (64q x 64k) frag-ordered
  __shared__ unsigned short lKV[2][4][4][512];   // 32 KB: 2 bufs x wave x {K0,K1,V0,V1} x 1KB
  const int tid = threadIdx.x, lane = tid & 63, wave = tid >> 6;
  const int h = blockIdx.x, b = blockIdx.z;
  const int q0 = blockIdx.y * 64;

  const size_t headf = (size_t)(b * H_ + h) * (PERHEAD / 8);  // short8 units
  short8 qf[4][2];
#pragma unroll
  for (int qb = 0; qb < 4; ++qb) {
    const short8* qp = (const short8*)Qf + headf + ((q0 >> 4) + qb) * 128 + lane;
    qf[qb][0] = qp[0];
    qf[qb][1] = qp[64];
  }
  // per-lane global pointers (16B per lane per fragment)
  const short8* kp = (const short8*)Kf + headf + wave * 128 + lane;  // += 512/iter
  const short8* vp = (const short8*)Vf + headf + wave * 64 + lane;   // += 512/iter
  const unsigned short* zp = Zl + ((size_t)b * S_ + q0 + (lane & 15)) * S_
                             + wave * 16 + ((lane >> 4) << 2);

  // P write offset (ushort units, within one 4096 tile region): fragment-ordered
  const int pw_off = ((wave >> 1) << 9)
                   + (((lane & 15) | (((wave & 1) << 1 | ((lane >> 4) >> 1)) << 4)) << 3)
                   + (((lane >> 4) & 1) << 2);

  floatx4 xacc[4] = {};  // x^T[dk = wave*16 + row][q = qb*16 + col]

  // prologue: stage tile 0 into buf 0, Zl depth-1 prefetch as r0
  gload_lds16(kp,       &lKV[0][wave][0][0]);
  gload_lds16(kp + 64,  &lKV[0][wave][1][0]);
  gload_lds16(vp,       &lKV[0][wave][2][0]);
  gload_lds16(vp + 256, &lKV[0][wave][3][0]);
  kp += 512; vp += 512;
  uint2 cz0 = *(const uint2*)(zp);
  uint2 cz1 = *(const uint2*)(zp + (size_t)16 * S_);
  uint2 cz2 = *(const uint2*)(zp + (size_t)32 * S_);
  uint2 cz3 = *(const uint2*)(zp + (size_t)48 * S_);
  zp += 64;
  __syncthreads();  // drains prologue staging (vmcnt(0) before barrier)

#pragma unroll 2
  for (int kt = 0; kt < S_ / 64; ++kt) {
    const int sb = kt & 1;           // K/V buf holding tile kt
    const int buf = (kt & 1) << 12;  // P buf
    // stage tile kt+1 into lKV[sb^1] (wave-private; drained by this iter's barrier)
    if (kt != S_ / 64 - 1) {
      gload_lds16(kp,       &lKV[sb ^ 1][wave][0][0]);
      gload_lds16(kp + 64,  &lKV[sb ^ 1][wave][1][0]);
      gload_lds16(vp,       &lKV[sb ^ 1][wave][2][0]);
      gload_lds16(vp + 256, &lKV[sb ^ 1][wave][3][0]);
      kp += 512; vp += 512;
    }
    // Zl prefetch for next iter (named registers, rotated under unroll)
    uint2 nz0, nz1, nz2, nz3;
    if (kt != S_ / 64 - 1) {
      nz0 = *(const uint2*)(zp);
      nz1 = *(const uint2*)(zp + (size_t)16 * S_);
      nz2 = *(const uint2*)(zp + (size_t)32 * S_);
      nz3 = *(const uint2*)(zp + (size_t)48 * S_);
      zp += 64;
    }

    // current tile K/V from LDS (conflict-free lane*16 reads; staged last iter)
    short8 ck0 = *(const short8*)&lKV[sb][wave][0][lane * 8];
    short8 ck1 = *(const short8*)&lKV[sb][wave][1][lane * 8];
    short8 cv0 = *(const short8*)&lKV[sb][wave][2][lane * 8];
    short8 cv1 = *(const short8*)&lKV[sb][wave][3][lane * 8];

    // S^T tiles: m = 16 keys (wave's), n = 64 q
    floatx4 sacc[4] = {};
#pragma unroll
    for (int qb = 0; qb < 4; ++qb) {
      sacc[qb] = MFMA16(ck0, qf[qb][0], sacc[qb]);
      sacc[qb] = MFMA16(ck1, qf[qb][1], sacc[qb]);
    }
    // P = exp2(s*C - Lz) -> bf16, fragment-ordered in LDS
#pragma unroll
    for (int qb = 0; qb < 4; ++qb) {
      uint2 zz = (qb == 0) ? cz0 : (qb == 1) ? cz1 : (qb == 2) ? cz2 : cz3;
      union { uint2 v; _Float16 hv[4]; } za; za.v = zz;
      float e0 = exp2f(fmaf(sacc[qb][0], EXP2SCALE, -(float)za.hv[0]));
      float e1 = exp2f(fmaf(sacc[qb][1], EXP2SCALE, -(float)za.hv[1]));
      float e2 = exp2f(fmaf(sacc[qb][2], EXP2SCALE, -(float)za.hv[2]));
      float e3 = exp2f(fmaf(sacc[qb][3], EXP2SCALE, -(float)za.hv[3]));
      uint2 p;
      p.x = pack_bf16_rhu(e0, e1);
      p.y = pack_bf16_rhu(e2, e3);
      *(uint2*)&lP[buf + (qb << 10) + pw_off] = p;
    }
    __syncthreads();  // P visible to all waves; ALSO drains this iter's staging

    // x^T += V_frag @ P  (conflict-free lane*16 reads)
#pragma unroll
    for (int qb = 0; qb < 4; ++qb) {
      short8 p0 = *(const short8*)&lP[buf + (qb << 10) + (lane << 3)];
      short8 p1 = *(const short8*)&lP[buf + (qb << 10) + 512 + (lane << 3)];
      xacc[qb] = MFMA16(cv0, p0, xacc[qb]);
      xacc[qb] = MFMA16(cv1, p1, xacc[qb]);
    }

    // rotate Zl prefetch -> current (renames under unroll)
    cz0 = nz0; cz1 = nz1; cz2 = nz2; cz3 = nz3;
  }

  // epilogue: transpose x^T -> x via padded LDS, then coalesced 16B stores
  __syncthreads();
  unsigned short* lX = lP;  // 64 rows(q) x 72 (dk padded)
#pragma unroll
  for (int qb = 0; qb < 4; ++qb)
#pragma unroll
    for (int r = 0; r < 4; ++r) {
      int q  = qb * 16 + (lane & 15);
      int dk = wave * 16 + (lane >> 4) * 4 + r;
      lX[q * 72 + dk] = f2bf(xacc[qb][r]);
    }
  __syncthreads();
  {
    int q = tid >> 2, cg = (tid & 3) * 16;
    short8 v0 = *(const short8*)&lX[q * 72 + cg];
    short8 v1 = *(const short8*)&lX[q * 72 + cg + 8];
    unsigned short* o = X + (size_t)(b * S_ + q0 + q) * D_ + h * DK_ + cg;
    *(short8*)&o[0] = v0;
    *(short8*)&o[8] = v1;
  }
}

// ---------------- launch ----------------
extern "C" void kernel_launch(void* const* d_in, const int* in_sizes, int n_in,
                              void* d_out, int out_size, void* d_ws, size_t ws_size,
                              hipStream_t stream) {
  const float* qi = (const float*)d_in[0];
  const float* ki = (const float*)d_in[1];
  const float* vi = (const float*)d_in[2];
  // d_in[3] = mask: reference discards masked_fill result -> unused
  const float* Wq = (const float*)d_in[4];
  const float* Wk = (const float*)d_in[5];
  const float* Wv = (const float*)d_in[6];
  const float* Wo = (const float*)d_in[7];

  const size_t NT = (size_t)B_ * S_ * D_;  // 4,194,304
  const size_t NW = (size_t)D_ * D_;       // 1,048,576

  unsigned short* w = (unsigned short*)d_ws;
  unsigned short* qi_bf = w; w += NT;
  unsigned short* ki_bf = w; w += NT;
  unsigned short* vi_bf = w; w += NT;
  unsigned short* Wq_bf = w; w += NW;
  unsigned short* Wk_bf = w; w += NW;
  unsigned short* Wv_bf = w; w += NW;
  unsigned short* Wo_bf = w; w += NW;
  unsigned short* Qf = w; w += NT;  // fragment-ordered per (b,h)
  unsigned short* Kf = w; w += NT;
  unsigned short* Vf = w; w += NT;
  unsigned short* Xb = w; w += NT;  // [b,s,e] row-major bf16
  unsigned short* Zl = w;           // [b,q,k] fp16 log2(Z), 16 MiB

  {
    int n4tok = (int)(NT / 4);  // 1048576 quads
    int n4w   = (int)(NW / 4);  // 262144 quads
    cast_all<<<dim3((n4tok + 255) / 256, 1, 7), 256, 0, stream>>>(
        qi, ki, vi, Wq, Wk, Wv, Wo,
        qi_bf, ki_bf, vi_bf, Wq_bf, Wk_bf, Wv_bf, Wo_bf, n4tok, n4w);
  }

  gemm_qkv<<<dim3(D_ / 128, (B_ * S_) / 128, 3), 256, 0, stream>>>(
      qi_bf, ki_bf, vi_bf, Wq_bf, Wk_bf, Wv_bf, Qf, Kf, Vf);

  compute_z<<<dim3(S_ / 64, S_ / 128, B_), 256, 0, stream>>>(Qf, Kf, Zl);
  attn_pv<<<dim3(H_, S_ / 64, B_), 256, 0, stream>>>(Qf, Kf, Vf, Zl, Xb);

  gemm_out<<<dim3(8, 64), 256, 0, stream>>>(Xb, Wo_bf, (float*)d_out);
}

// Round 12
// 300.099 us; speedup vs baseline: 1.0560x; 1.0560x over previous
//
#include <hip/hip_runtime.h>
#include <stdint.h>

// Problem constants (reference: B=2, S=2048, D=1024, H=16, DK=64)
#define B_  2
#define S_  2048
#define D_  1024
#define H_  16
#define DK_ 64
#define PERHEAD (S_ * DK_)  // 131072 elems per (b,h)

// exp(x*0.125) = exp2(x * 0.125*log2(e))
#define EXP2SCALE 0.18033688011112042f

typedef __attribute__((ext_vector_type(8))) short short8;   // 8 bf16 = 4 VGPRs (MFMA A/B frag)
typedef __attribute__((ext_vector_type(4))) float floatx4;  // MFMA C/D frag

#define MFMA16(a, b, c) __builtin_amdgcn_mfma_f32_16x16x32_bf16((a), (b), (c), 0, 0, 0)

// async global->LDS, 16B per lane (used only in the projection GEMMs)
__device__ __forceinline__ void gload_lds16(const void* g, void* lds) {
  __builtin_amdgcn_global_load_lds(
      (__attribute__((address_space(1))) void*)(void*)g,
      (__attribute__((address_space(3))) void*)lds, 16, 0, 0);
}

__device__ __forceinline__ unsigned short f2bf(float f) {
  union { float f; unsigned int u; } v;
  v.f = f;
  unsigned int r = v.u + 0x7fffu + ((v.u >> 16) & 1u);
  return (unsigned short)(r >> 16);
}

// pack two positive f32 into two bf16 (round-half-up: +0x8000 then take hi16 via v_perm)
__device__ __forceinline__ unsigned int pack_bf16_rhu(float e0, float e1) {
  unsigned int u0 = __float_as_uint(e0) + 0x8000u;
  unsigned int u1 = __float_as_uint(e1) + 0x8000u;
  return __builtin_amdgcn_perm(u1, u0, 0x07060302);  // {u1.hi16, u0.hi16}
}

// ---------------- single batched cast fp32 -> bf16 (7 tensors, one launch) ----------
// z 0..2: token inputs (n4 = NT/4 quads); z 3..6: weights (n4w = NW/4 quads).
__global__ void cast_all(const float* __restrict__ a0, const float* __restrict__ a1,
                         const float* __restrict__ a2, const float* __restrict__ a3,
                         const float* __restrict__ a4, const float* __restrict__ a5,
                         const float* __restrict__ a6,
                         unsigned short* __restrict__ o0, unsigned short* __restrict__ o1,
                         unsigned short* __restrict__ o2, unsigned short* __restrict__ o3,
                         unsigned short* __restrict__ o4, unsigned short* __restrict__ o5,
                         unsigned short* __restrict__ o6,
                         int n4tok, int n4w) {
  const int z = blockIdx.z;
  const float* in = (z == 0) ? a0 : (z == 1) ? a1 : (z == 2) ? a2 : (z == 3) ? a3
                    : (z == 4) ? a4 : (z == 5) ? a5 : a6;
  unsigned short* out = (z == 0) ? o0 : (z == 1) ? o1 : (z == 2) ? o2 : (z == 3) ? o3
                        : (z == 4) ? o4 : (z == 5) ? o5 : o6;
  const int n4 = (z < 3) ? n4tok : n4w;
  int i = blockIdx.x * 256 + threadIdx.x;
  if (i < n4) {
    float4 f = ((const float4*)in)[i];
    uint2 p;
    p.x = (unsigned int)f2bf(f.x) | ((unsigned int)f2bf(f.y) << 16);
    p.y = (unsigned int)f2bf(f.z) | ((unsigned int)f2bf(f.w) << 16);
    ((uint2*)out)[i] = p;
  }
}

// Fragment-ordered layouts (16x16x32 MFMA operand fragments; one frag = 16 rows x
// 32 k x bf16 = 512 elems = 64 lane-ordered 16B chunks; chunk L = row(L&15),
// k = (L>>4)*8..+7). Reader: ds/global _b128 at base + lane*16 -> conflict-free.
//
// Qf/Kf per (b,h): frag(sblk = s>>4, ks = dk>>5):  idx = sblk*2 + ks
// Vf    per (b,h): frag(kblk = key>>5, db = dk>>4): idx = kblk*4 + db  (rows = dk)

// ---------------- shared GEMM core: 128x128 tile, BK=32, 4 waves each 64x64 ----------
__device__ __forceinline__ void gemm_core(const unsigned short* __restrict__ A,
                                          const unsigned short* __restrict__ Bw,
                                          unsigned short* lA, unsigned short* lB,
                                          int m0, int n0, int tid, int lane, int wave,
                                          floatx4 acc[4][4]) {
  const int wm = (wave >> 1) * 64;
  const int wn = (wave & 1) * 64;
  for (int k0 = 0; k0 < D_; k0 += 32) {
#pragma unroll
    for (int l = 0; l < 2; ++l) {
      int c = l * 256 + tid;
      int row = c >> 2, cb = (c & 3) * 16;
      const char* ga = (const char*)A + ((size_t)(m0 + row) * D_ + k0) * 2 + cb;
      gload_lds16(ga, (char*)lA + (size_t)(l * 256 + wave * 64) * 16);
      const char* gb = (const char*)Bw + ((size_t)(n0 + row) * D_ + k0) * 2 + cb;
      gload_lds16(gb, (char*)lB + (size_t)(l * 256 + wave * 64) * 16);
    }
    __syncthreads();
    short8 af[4], bf_[4];
#pragma unroll
    for (int mt = 0; mt < 4; ++mt)
      af[mt] = *(const short8*)&lA[(wm + mt * 16 + (lane & 15)) * 32 + (lane >> 4) * 8];
#pragma unroll
    for (int nt = 0; nt < 4; ++nt)
      bf_[nt] = *(const short8*)&lB[(wn + nt * 16 + (lane & 15)) * 32 + (lane >> 4) * 8];
#pragma unroll
    for (int mt = 0; mt < 4; ++mt)
#pragma unroll
      for (int nt = 0; nt < 4; ++nt)
        acc[mt][nt] = MFMA16(af[mt], bf_[nt], acc[mt][nt]);
    __syncthreads();
  }
}

// ---------------- fused QKV projection: z selects (A, W, Out, epilogue) ----------------
// XCD swizzle (r8): XCD owns m-tiles [xcd*4, xcd*4+4) for all n, z slowest ->
// hot set ~3 MB (A panel 1 MB + B 2 MB), L2-resident. 768 = 8 xcd x 8 n x 4 m x 3 z.
// (256,3) since r9: grid = exactly 3 blocks/CU.
__launch_bounds__(256, 3)
__global__ void gemm_qkv(const unsigned short* __restrict__ qi, const unsigned short* __restrict__ ki,
                         const unsigned short* __restrict__ vi,
                         const unsigned short* __restrict__ Wq, const unsigned short* __restrict__ Wk,
                         const unsigned short* __restrict__ Wv,
                         unsigned short* __restrict__ Qf, unsigned short* __restrict__ Kf,
                         unsigned short* __restrict__ Vf) {
  __shared__ unsigned short lA[128 * 32];
  __shared__ unsigned short lB[128 * 32];
  const int f = blockIdx.x + 8 * blockIdx.y + 256 * blockIdx.z;
  const int xcd = f & 7, j = f >> 3;              // j in [0,96)
  const int n0 = (j & 7) * 128;                   // n-tile
  const int m0 = (xcd * 4 + ((j >> 3) & 3)) * 128;  // m-tile: XCD-chunked
  const int z  = j >> 5;                          // 0..2, slowest
  const unsigned short* A  = (z == 0) ? qi : (z == 1) ? ki : vi;
  const unsigned short* Bw = (z == 0) ? Wq : (z == 1) ? Wk : Wv;
  unsigned short* O        = (z == 0) ? Qf : (z == 1) ? Kf : Vf;
  const int tid = threadIdx.x, lane = tid & 63, wave = tid >> 6;
  const int wm = (wave >> 1) * 64, wn = (wave & 1) * 64;

  floatx4 acc[4][4] = {};
  gemm_core(A, Bw, lA, lB, m0, n0, tid, lane, wave, acc);

  if (z < 2) {  // Qf/Kf fragment layout
#pragma unroll
    for (int mt = 0; mt < 4; ++mt)
#pragma unroll
      for (int nt = 0; nt < 4; ++nt)
#pragma unroll
        for (int r = 0; r < 4; ++r) {
          int row = m0 + wm + mt * 16 + (lane >> 4) * 4 + r;  // token
          int col = n0 + wn + nt * 16 + (lane & 15);          // e
          int b = row >> 11, s = row & (S_ - 1);
          int h = col >> 6,  dk = col & 63;
          size_t base = (size_t)(b * H_ + h) * PERHEAD;
          int frag = (s >> 4) * 2 + (dk >> 5);
          int lp = (s & 15) | (((dk >> 3) & 3) << 4);
          O[base + (size_t)frag * 512 + lp * 8 + (dk & 7)] = f2bf(acc[mt][nt][r]);
        }
  } else {  // Vf fragment layout (rows = dk, k = key)
#pragma unroll
    for (int mt = 0; mt < 4; ++mt)
#pragma unroll
      for (int nt = 0; nt < 4; ++nt) {
        int row0 = m0 + wm + mt * 16 + (lane >> 4) * 4;  // 4 consecutive keys
        int col  = n0 + wn + nt * 16 + (lane & 15);
        int b = row0 >> 11, key0 = row0 & (S_ - 1);
        int h = col >> 6,   dk = col & 63;
        size_t base = (size_t)(b * H_ + h) * PERHEAD;
        int frag = (key0 >> 5) * 4 + (dk >> 4);
        int lp = (dk & 15) | (((key0 >> 3) & 3) << 4);
        unsigned long long pk =
            (unsigned long long)f2bf(acc[mt][nt][0]) |
            ((unsigned long long)f2bf(acc[mt][nt][1]) << 16) |
            ((unsigned long long)f2bf(acc[mt][nt][2]) << 32) |
            ((unsigned long long)f2bf(acc[mt][nt][3]) << 48);
        *(unsigned long long*)&O[base + (size_t)frag * 512 + lp * 8 + (key0 & 7)] = pk;
      }
  }
}

// ---------------- output projection: fp32 row-major ----------------
// r9: 64x128 tile, 512 blocks = 2/CU; XCD owns m-tiles [xcd*8, xcd*8+8).
__launch_bounds__(256, 2)
__global__ void gemm_out(const unsigned short* __restrict__ A, const unsigned short* __restrict__ Bw,
                         float* __restrict__ O) {
  __shared__ unsigned short lA[64 * 32];
  __shared__ unsigned short lB[128 * 32];
  const int f = blockIdx.x + 8 * blockIdx.y;      // grid (8, 64) = 512 blocks
  const int xcd = f & 7, j = f >> 3;              // j in [0,64)
  const int n0 = (j & 7) * 128;
  const int m0 = (xcd * 8 + (j >> 3)) * 64;       // m-tile (64 rows): XCD-chunked
  const int tid = threadIdx.x, lane = tid & 63, wave = tid >> 6;
  const int wm = (wave >> 1) * 32, wn = (wave & 1) * 64;
  floatx4 acc[2][4] = {};
  for (int k0 = 0; k0 < D_; k0 += 32) {
    {  // A: 64x32 tile = 256 x 16B chunks, one per thread
      int c = tid;
      int row = c >> 2, cb = (c & 3) * 16;
      const char* ga = (const char*)A + ((size_t)(m0 + row) * D_ + k0) * 2 + cb;
      gload_lds16(ga, (char*)lA + (size_t)(wave * 64) * 16);
    }
#pragma unroll
    for (int l = 0; l < 2; ++l) {  // B: 128x32 tile = 512 chunks, two per thread
      int c = l * 256 + tid;
      int row = c >> 2, cb = (c & 3) * 16;
      const char* gb = (const char*)Bw + ((size_t)(n0 + row) * D_ + k0) * 2 + cb;
      gload_lds16(gb, (char*)lB + (size_t)(l * 256 + wave * 64) * 16);
    }
    __syncthreads();
    short8 af[2], bf_[4];
#pragma unroll
    for (int mt = 0; mt < 2; ++mt)
      af[mt] = *(const short8*)&lA[(wm + mt * 16 + (lane & 15)) * 32 + (lane >> 4) * 8];
#pragma unroll
    for (int nt = 0; nt < 4; ++nt)
      bf_[nt] = *(const short8*)&lB[(wn + nt * 16 + (lane & 15)) * 32 + (lane >> 4) * 8];
#pragma unroll
    for (int mt = 0; mt < 2; ++mt)
#pragma unroll
      for (int nt = 0; nt < 4; ++nt)
        acc[mt][nt] = MFMA16(af[mt], bf_[nt], acc[mt][nt]);
    __syncthreads();
  }
#pragma unroll
  for (int mt = 0; mt < 2; ++mt)
#pragma unroll
    for (int nt = 0; nt < 4; ++nt)
#pragma unroll
      for (int r = 0; r < 4; ++r) {
        int row = m0 + wm + mt * 16 + (lane >> 4) * 4 + r;
        int col = n0 + wn + nt * 16 + (lane & 15);
        O[(size_t)row * D_ + col] = acc[mt][nt][r];
      }
}

// ---------------- Pass 1: Zl[b,q,k] = fp16( log2( sum_h exp2(s*C) ) ) ----------------
// r8: k-tile 64, 1024 blocks = 4 blocks/CU, (256,4). Kept (part of 301.0 best).
__launch_bounds__(256, 4)
__global__ void compute_z(const unsigned short* __restrict__ Qf,
                          const unsigned short* __restrict__ Kf,
                          unsigned short* __restrict__ Zl) {
  const int tid = threadIdx.x, lane = tid & 63, wave = tid >> 6;
  const int k0 = blockIdx.x * 64, q0 = blockIdx.y * 128, b = blockIdx.z;

  floatx4 zacc[2][4] = {};
  const short8* qbase = (const short8*)Qf + (size_t)b * H_ * (PERHEAD / 8)
                        + ((q0 >> 4) + wave * 2) * 128 + lane;
  const short8* kbase = (const short8*)Kf + (size_t)b * H_ * (PERHEAD / 8)
                        + (k0 >> 4) * 128 + lane;

#pragma unroll 1
  for (int h = 0; h < H_; ++h) {
    short8 qf0 = qbase[0], qf1 = qbase[64];    // sq=0, ks=0/1
    short8 qf2 = qbase[128], qf3 = qbase[192]; // sq=1, ks=0/1
    short8 kst[4][2];
#pragma unroll
    for (int kb = 0; kb < 4; ++kb) {
      kst[kb][0] = kbase[kb * 128];
      kst[kb][1] = kbase[kb * 128 + 64];
    }
#pragma unroll
    for (int kb = 0; kb < 4; ++kb) {
      floatx4 s0 = {}, s1 = {};
      s0 = MFMA16(qf0, kst[kb][0], s0);
      s0 = MFMA16(qf1, kst[kb][1], s0);
      s1 = MFMA16(qf2, kst[kb][0], s1);
      s1 = MFMA16(qf3, kst[kb][1], s1);
#pragma unroll
      for (int r = 0; r < 4; ++r) {
        zacc[0][kb][r] += exp2f(s0[r] * EXP2SCALE);
        zacc[1][kb][r] += exp2f(s1[r] * EXP2SCALE);
      }
    }
    qbase += PERHEAD / 8;
    kbase += PERHEAD / 8;
  }

#pragma unroll
  for (int sq = 0; sq < 2; ++sq)
#pragma unroll
    for (int kb = 0; kb < 4; ++kb)
#pragma unroll
      for (int r = 0; r < 4; ++r) {
        int q = q0 + wave * 32 + sq * 16 + (lane >> 4) * 4 + r;
        int k = k0 + kb * 16 + (lane & 15);
        union { _Float16 h; unsigned short u; } cv;
        cv.h = (_Float16)log2f(zacc[sq][kb][r]);
        Zl[((size_t)b * S_ + q) * S_ + k] = cv.u;
      }
}

// ---------------- Pass 2: x^T = exp2(s*C - Lz) @ V ----------------
// EXACT r0 body + (256,4) bound (r10 config, session best: total 301.0 us,
// attn_pv 89.7). Structural floor: 10 variants (occupancy x3, barrier count,
// barrier-free in-register, SGB pin, XCD swizzle, global_load_lds staging) all
// regressed or null. The serial QK->exp->LDS->barrier->PV chain over ~2.7
// dispatcher-sustained blocks/CU is the floor; head-axis softmax forces the
// two-pass structure (fusion needs 256 f32/lane state or per-tile cross-wave
// Z reduction).
// Head partition preserved (f mod 8 = h mod 8 -> 2 MB K/V per XCD, L2-resident).
__launch_bounds__(256, 4)
__global__ void attn_pv(const unsigned short* __restrict__ Qf,
                        const unsigned short* __restrict__ Kf,
                        const unsigned short* __restrict__ Vf,
                        const unsigned short* __restrict__ Zl,
                        unsigned short* __restrict__ X) {
  __shared__ unsigned short lP[2 * 4096];  // 2 bufs x (64q x 64k) fragment-ordered
  const int tid = threadIdx.x, lane = tid & 63, wave = tid >> 6;
  const int h = blockIdx.x, b = blockIdx.z;
  const int q0 = blockIdx.y * 64;

  const size_t headf = (size_t)(b * H_ + h) * (PERHEAD / 8);  // short8 units
  short8 qf[4][2];
#pragma unroll
  for (int qb = 0; qb < 4; ++qb) {
    const short8* qp = (const short8*)Qf + headf + ((q0 >> 4) + qb) * 128 + lane;
    qf[qb][0] = qp[0];
    qf[qb][1] = qp[64];
  }
  const short8* kp = (const short8*)Kf + headf + wave * 128 + lane;  // += 512/iter
  const short8* vp = (const short8*)Vf + headf + wave * 64 + lane;   // += 512/iter
  const unsigned short* zp = Zl + ((size_t)b * S_ + q0 + (lane & 15)) * S_
                             + wave * 16 + ((lane >> 4) << 2);

  // P write offset (ushort units, within one 4096 tile region): fragment-ordered
  const int pw_off = ((wave >> 1) << 9)
                   + (((lane & 15) | (((wave & 1) << 1 | ((lane >> 4) >> 1)) << 4)) << 3)
                   + (((lane >> 4) & 1) << 2);

  floatx4 xacc[4] = {};  // x^T[dk = wave*16 + row][q = qb*16 + col]

  // prologue: load iteration 0's operands
  short8 ck0 = kp[0], ck1 = kp[64];
  short8 cv0 = vp[0], cv1 = vp[256];
  uint2 cz0 = *(const uint2*)(zp);
  uint2 cz1 = *(const uint2*)(zp + (size_t)16 * S_);
  uint2 cz2 = *(const uint2*)(zp + (size_t)32 * S_);
  uint2 cz3 = *(const uint2*)(zp + (size_t)48 * S_);
  kp += 512; vp += 512; zp += 64;

#pragma unroll 2
  for (int kt = 0; kt < S_ / 64; ++kt) {
    const int buf = (kt & 1) << 12;
    // prefetch next iteration (named registers; guarded on last iter)
    short8 nk0, nk1, nv0, nv1;
    uint2 nz0, nz1, nz2, nz3;
    if (kt != S_ / 64 - 1) {
      nk0 = kp[0];  nk1 = kp[64];
      nv0 = vp[0];  nv1 = vp[256];
      nz0 = *(const uint2*)(zp);
      nz1 = *(const uint2*)(zp + (size_t)16 * S_);
      nz2 = *(const uint2*)(zp + (size_t)32 * S_);
      nz3 = *(const uint2*)(zp + (size_t)48 * S_);
      kp += 512; vp += 512; zp += 64;
    }

    // S^T tiles: m = 16 keys (wave's), n = 64 q
    floatx4 sacc[4] = {};
#pragma unroll
    for (int qb = 0; qb < 4; ++qb) {
      sacc[qb] = MFMA16(ck0, qf[qb][0], sacc[qb]);
      sacc[qb] = MFMA16(ck1, qf[qb][1], sacc[qb]);
    }
    // P = exp2(s*C - Lz) -> bf16, fragment-ordered in LDS
#pragma unroll
    for (int qb = 0; qb < 4; ++qb) {
      uint2 zz = (qb == 0) ? cz0 : (qb == 1) ? cz1 : (qb == 2) ? cz2 : cz3;
      union { uint2 v; _Float16 hv[4]; } za; za.v = zz;
      float e0 = exp2f(fmaf(sacc[qb][0], EXP2SCALE, -(float)za.hv[0]));
      float e1 = exp2f(fmaf(sacc[qb][1], EXP2SCALE, -(float)za.hv[1]));
      float e2 = exp2f(fmaf(sacc[qb][2], EXP2SCALE, -(float)za.hv[2]));
      float e3 = exp2f(fmaf(sacc[qb][3], EXP2SCALE, -(float)za.hv[3]));
      uint2 p;
      p.x = pack_bf16_rhu(e0, e1);
      p.y = pack_bf16_rhu(e2, e3);
      *(uint2*)&lP[buf + (qb << 10) + pw_off] = p;
    }
    __syncthreads();

    // x^T += V_frag @ P  (conflict-free lane*16 reads)
#pragma unroll
    for (int qb = 0; qb < 4; ++qb) {
      short8 p0 = *(const short8*)&lP[buf + (qb << 10) + (lane << 3)];
      short8 p1 = *(const short8*)&lP[buf + (qb << 10) + 512 + (lane << 3)];
      xacc[qb] = MFMA16(cv0, p0, xacc[qb]);
      xacc[qb] = MFMA16(cv1, p1, xacc[qb]);
    }

    // rotate prefetched -> current (renames under unroll)
    ck0 = nk0; ck1 = nk1; cv0 = nv0; cv1 = nv1;
    cz0 = nz0; cz1 = nz1; cz2 = nz2; cz3 = nz3;
  }

  // epilogue: transpose x^T -> x via padded LDS, then coalesced 16B stores
  __syncthreads();
  unsigned short* lX = lP;  // 64 rows(q) x 72 (dk padded)
#pragma unroll
  for (int qb = 0; qb < 4; ++qb)
#pragma unroll
    for (int r = 0; r < 4; ++r) {
      int q  = qb * 16 + (lane & 15);
      int dk = wave * 16 + (lane >> 4) * 4 + r;
      lX[q * 72 + dk] = f2bf(xacc[qb][r]);
    }
  __syncthreads();
  {
    int q = tid >> 2, cg = (tid & 3) * 16;
    short8 v0 = *(const short8*)&lX[q * 72 + cg];
    short8 v1 = *(const short8*)&lX[q * 72 + cg + 8];
    unsigned short* o = X + (size_t)(b * S_ + q0 + q) * D_ + h * DK_ + cg;
    *(short8*)&o[0] = v0;
    *(short8*)&o[8] = v1;
  }
}

// ---------------- launch ----------------
extern "C" void kernel_launch(void* const* d_in, const int* in_sizes, int n_in,
                              void* d_out, int out_size, void* d_ws, size_t ws_size,
                              hipStream_t stream) {
  const float* qi = (const float*)d_in[0];
  const float* ki = (const float*)d_in[1];
  const float* vi = (const float*)d_in[2];
  // d_in[3] = mask: reference discards masked_fill result -> unused
  const float* Wq = (const float*)d_in[4];
  const float* Wk = (const float*)d_in[5];
  const float* Wv = (const float*)d_in[6];
  const float* Wo = (const float*)d_in[7];

  const size_t NT = (size_t)B_ * S_ * D_;  // 4,194,304
  const size_t NW = (size_t)D_ * D_;       // 1,048,576

  unsigned short* w = (unsigned short*)d_ws;
  unsigned short* qi_bf = w; w += NT;
  unsigned short* ki_bf = w; w += NT;
  unsigned short* vi_bf = w; w += NT;
  unsigned short* Wq_bf = w; w += NW;
  unsigned short* Wk_bf = w; w += NW;
  unsigned short* Wv_bf = w; w += NW;
  unsigned short* Wo_bf = w; w += NW;
  unsigned short* Qf = w; w += NT;  // fragment-ordered per (b,h)
  unsigned short* Kf = w; w += NT;
  unsigned short* Vf = w; w += NT;
  unsigned short* Xb = w; w += NT;  // [b,s,e] row-major bf16
  unsigned short* Zl = w;           // [b,q,k] fp16 log2(Z), 16 MiB

  {
    int n4tok = (int)(NT / 4);  // 1048576 quads
    int n4w   = (int)(NW / 4);  // 262144 quads
    cast_all<<<dim3((n4tok + 255) / 256, 1, 7), 256, 0, stream>>>(
        qi, ki, vi, Wq, Wk, Wv, Wo,
        qi_bf, ki_bf, vi_bf, Wq_bf, Wk_bf, Wv_bf, Wo_bf, n4tok, n4w);
  }

  gemm_qkv<<<dim3(D_ / 128, (B_ * S_) / 128, 3), 256, 0, stream>>>(
      qi_bf, ki_bf, vi_bf, Wq_bf, Wk_bf, Wv_bf, Qf, Kf, Vf);

  compute_z<<<dim3(S_ / 64, S_ / 128, B_), 256, 0, stream>>>(Qf, Kf, Zl);
  attn_pv<<<dim3(H_, S_ / 64, B_), 256, 0, stream>>>(Qf, Kf, Vf, Zl, Xb);

  gemm_out<<<dim3(8, 64), 256, 0, stream>>>(Xb, Wo_bf, (float*)d_out);
}